// Round 1
// baseline (255.107 us; speedup 1.0000x reference)
//
#include <hip/hip_runtime.h>

#define B_ 16
#define N_ 128
#define A_ 32
#define O_ 64
#define VD_ 768
#define H_ 1024

// ---------------------------------------------------------------------------
// NT GEMM: out[M, 1024] = X[M, 768] @ Wt[1024, 768]^T, optional epilogue
// EPI=1: out = relu(x + bias[h]) * scale[h]
// Block: 256 threads computes a 64x64 output tile. K staged in 64-chunks.
// LDS layout XOR-swizzled in 16B units to tame bank conflicts.
// ---------------------------------------------------------------------------
template<int EPI>
__global__ __launch_bounds__(256)
void nt_gemm(const float* __restrict__ X, const float* __restrict__ Wt,
             const float* __restrict__ bias, const float* __restrict__ scale,
             float* __restrict__ out)
{
    __shared__ float Xl[64][64];
    __shared__ float Wl[64][64];
    const int r0 = blockIdx.x * 64;
    const int h0 = blockIdx.y * 64;
    const int tid = threadIdx.x;
    const int srow = tid >> 2;   // 0..63
    const int sq   = tid & 3;    // 0..3 (16-float chunk)
    const float* xrow = X  + (size_t)(r0 + srow) * VD_;
    const float* wrow = Wt + (size_t)(h0 + srow) * VD_;
    const int og = tid >> 4;     // 0..15 : row group (4 rows)
    const int hg = tid & 15;     // 0..15 : col group (4 cols)
    float acc[4][4] = {};

    for (int d0 = 0; d0 < VD_; d0 += 64) {
        __syncthreads();   // protect LDS from previous iteration's readers
        #pragma unroll
        for (int j = 0; j < 4; ++j) {
            const int u  = sq * 4 + j;            // 16B unit within row
            const int us = u ^ (srow & 15);       // swizzle
            *(float4*)&Xl[srow][us * 4] = *(const float4*)(xrow + d0 + u * 4);
            *(float4*)&Wl[srow][us * 4] = *(const float4*)(wrow + d0 + u * 4);
        }
        __syncthreads();
        #pragma unroll 4
        for (int kq = 0; kq < 16; ++kq) {
            float4 a[4], bb[4];
            #pragma unroll
            for (int i = 0; i < 4; ++i) {
                const int r = og * 4 + i;
                const int c = hg * 4 + i;
                a[i]  = *(const float4*)&Xl[r][(kq ^ (r & 15)) * 4];
                bb[i] = *(const float4*)&Wl[c][(kq ^ (c & 15)) * 4];
            }
            #pragma unroll
            for (int i = 0; i < 4; ++i)
                #pragma unroll
                for (int j = 0; j < 4; ++j)
                    acc[i][j] += a[i].x * bb[j].x + a[i].y * bb[j].y
                               + a[i].z * bb[j].z + a[i].w * bb[j].w;
        }
    }

    #pragma unroll
    for (int i = 0; i < 4; ++i) {
        const int r = r0 + og * 4 + i;
        const int h = h0 + hg * 4;
        float4 v;
        float* vp = (float*)&v;
        #pragma unroll
        for (int j = 0; j < 4; ++j) {
            float val = acc[i][j];
            if (EPI) val = fmaxf(val + bias[h + j], 0.0f) * scale[h + j];
            vp[j] = val;
        }
        *(float4*)(out + (size_t)r * H_ + h) = v;
    }
}

// ---------------------------------------------------------------------------
// Fused main kernel. One block per (b, n-pair): 64 rows = 2 n's x 32 a's.
// logits[row] = sum_h relu(att1_row . W[b][:,h] + vb[h]) * u[b,n,h]  (+lb)/t
// then masked softmax over a and out[b,n,:] = att2 @ att1.
// ---------------------------------------------------------------------------
__global__ __launch_bounds__(256)
void fused_att(const float* __restrict__ att1, const float* __restrict__ Wb,
               const float* __restrict__ ub, const float* __restrict__ vb,
               const int* __restrict__ tags, const int* __restrict__ tptr,
               const float* __restrict__ lbptr, float* __restrict__ out)
{
    __shared__ float aT[64][64];    // [o][row]  (transposed att1 tile)
    __shared__ float ao[64][64];    // [row][o]  (original layout, for epilogue)
    __shared__ float Wl[64][128];   // [o][h-tile], swizzled
    __shared__ float lg[64];
    __shared__ float sml[64];

    const int blk = blockIdx.x;     // 0..1023
    const int b   = blk >> 6;
    const int n0  = (blk & 63) * 2;
    const int tid = threadIdx.x;

    // stage att1 tile in both layouts (rows = n-pair's 64 (a) rows, contiguous)
    {
        const int row = tid >> 2, q = tid & 3;
        const float* src = att1 + ((size_t)(b * N_ + n0) * A_ + row) * O_ + q * 16;
        #pragma unroll
        for (int j = 0; j < 4; ++j) {
            float4 v = *(const float4*)(src + 4 * j);
            *(float4*)&ao[row][q * 16 + 4 * j] = v;
            aT[q * 16 + 4 * j + 0][row] = v.x;
            aT[q * 16 + 4 * j + 1][row] = v.y;
            aT[q * 16 + 4 * j + 2][row] = v.z;
            aT[q * 16 + 4 * j + 3][row] = v.w;
        }
    }

    const int rg = tid >> 5;        // 0..7 : rows rg*8 .. rg*8+7
    const int hg = tid & 31;        // 0..31: cols hg*4 .. hg*4+3 of h-tile
    const int nl = rg >> 2;         // which n of the pair this thread's rows use
    const float* urow = ub + (size_t)(b * N_ + n0 + nl) * H_;
    float part[8] = {};

    for (int ht = 0; ht < 8; ++ht) {
        const int h0 = ht * 128;
        __syncthreads();            // protect Wl (and att1 tiles on iter 0)
        #pragma unroll
        for (int j = 0; j < 8; ++j) {
            const int f = tid + 256 * j;     // float4 index in 64x128 tile
            const int row = f >> 5;
            const int u = f & 31;
            const int us = u ^ (row & 7);    // swizzle
            *(float4*)&Wl[row][us * 4] =
                *(const float4*)(Wb + (size_t)(b * O_ + row) * H_ + h0 + u * 4);
        }
        __syncthreads();

        float acc[8][4] = {};
        #pragma unroll 4
        for (int k = 0; k < 64; ++k) {
            const float4 wv = *(const float4*)&Wl[k][(hg ^ (k & 7)) * 4];
            const float4 a0 = *(const float4*)&aT[k][rg * 8];
            const float4 a1 = *(const float4*)&aT[k][rg * 8 + 4];
            const float ar[8] = {a0.x, a0.y, a0.z, a0.w, a1.x, a1.y, a1.z, a1.w};
            #pragma unroll
            for (int i = 0; i < 8; ++i) {
                acc[i][0] += ar[i] * wv.x;
                acc[i][1] += ar[i] * wv.y;
                acc[i][2] += ar[i] * wv.z;
                acc[i][3] += ar[i] * wv.w;
            }
        }

        const int h = h0 + hg * 4;
        const float4 vbv = *(const float4*)(vb + h);
        const float4 uv  = *(const float4*)(urow + h);
        #pragma unroll
        for (int i = 0; i < 8; ++i) {
            part[i] += fmaxf(acc[i][0] + vbv.x, 0.f) * uv.x
                     + fmaxf(acc[i][1] + vbv.y, 0.f) * uv.y
                     + fmaxf(acc[i][2] + vbv.z, 0.f) * uv.z
                     + fmaxf(acc[i][3] + vbv.w, 0.f) * uv.w;
        }
    }

    // reduce partial logits across the 32 hg-lanes (within wave halves)
    #pragma unroll
    for (int i = 0; i < 8; ++i) {
        float v = part[i];
        v += __shfl_xor(v, 16, 64);
        v += __shfl_xor(v, 8, 64);
        v += __shfl_xor(v, 4, 64);
        v += __shfl_xor(v, 2, 64);
        v += __shfl_xor(v, 1, 64);
        if (hg == 0) lg[rg * 8 + i] = v;
    }
    __syncthreads();

    const float tf  = (float)(*tptr);
    const float lbv = *lbptr;
    if (tid < 64) {
        const int nn = tid >> 5, a = tid & 31;
        const float l = (lg[tid] + lbv) / tf;
        const int tg = tags[(size_t)(b * N_ + n0 + nn) * A_ + a];
        sml[tid] = (tg > 0) ? l : -1e30f;
    }
    __syncthreads();

    if (tid < 128) {
        const int nn = tid >> 6, o = tid & 63;
        const float* lr = &sml[nn * 32];
        float m = -3.0e38f;
        #pragma unroll
        for (int a = 0; a < 32; ++a) m = fmaxf(m, lr[a]);
        float s = 0.f, accum = 0.f;
        #pragma unroll
        for (int a = 0; a < 32; ++a) {
            const float e = __expf(lr[a] - m);
            s += e;
            accum += e * ao[nn * 32 + a][o];
        }
        out[(size_t)(b * N_ + n0 + nn) * O_ + o] = accum / s;
    }
}

extern "C" void kernel_launch(void* const* d_in, const int* in_sizes, int n_in,
                              void* d_out, int out_size, void* d_ws, size_t ws_size,
                              hipStream_t stream)
{
    const float* q    = (const float*)d_in[0];
    const float* att1 = (const float*)d_in[1];
    const float* obj  = (const float*)d_in[2];
    const int*   tags = (const int*)d_in[3];
    const int*   tptr = (const int*)d_in[4];
    const float* vw   = (const float*)d_in[5];
    const float* vb   = (const float*)d_in[6];
    const float* qw   = (const float*)d_in[7];
    const float* qb   = (const float*)d_in[8];
    const float* lw   = (const float*)d_in[9];
    const float* lb   = (const float*)d_in[10];
    float* out = (float*)d_out;

    float* Wb = (float*)d_ws;                          // [16*64, 1024]  (4 MB)
    float* ub = Wb + (size_t)B_ * O_ * H_;             // [16*128, 1024] (8 MB)

    // A: W[b,o,h] = sum_d obj[b,o,d] * vw[h,d]
    nt_gemm<0><<<dim3((B_ * O_) / 64, H_ / 64), 256, 0, stream>>>(
        obj, vw, nullptr, nullptr, Wb);
    // B: u[b,n,h] = relu(q[b,n,:].qw[h,:] + qb[h]) * lw[h]
    nt_gemm<1><<<dim3((B_ * N_) / 64, H_ / 64), 256, 0, stream>>>(
        q, qw, qb, lw, ub);
    // C: fused logits -> softmax -> att2 @ att1
    fused_att<<<(B_ * N_) / 2, 256, 0, stream>>>(
        att1, Wb, ub, vb, tags, tptr, lb, out);
}

// Round 2
// 94.380 us; speedup vs baseline: 2.7030x; 2.7030x over previous
//
#include <hip/hip_runtime.h>

#define B_ 16
#define N_ 128
#define A_ 32
#define O_ 64
#define VD_ 768
#define H_ 1024

typedef short s16x8 __attribute__((ext_vector_type(8)));
typedef short s16x4 __attribute__((ext_vector_type(4)));
typedef float f32x4 __attribute__((ext_vector_type(4)));

#define MFMA(a, b, c) __builtin_amdgcn_mfma_f32_16x16x32_bf16(a, b, c, 0, 0, 0)

__device__ __forceinline__ short bf_hi(float x) {
    return (short)(__float_as_uint(x) >> 16);
}
__device__ __forceinline__ short bf_lo(float x) {
    float r = x - __uint_as_float(__float_as_uint(x) & 0xffff0000u);
    return (short)(__float_as_uint(r) >> 16);
}
__device__ __forceinline__ void cvt8(const float4& f0, const float4& f1,
                                     s16x8& hi, s16x8& lo) {
    const float ff[8] = {f0.x, f0.y, f0.z, f0.w, f1.x, f1.y, f1.z, f1.w};
    #pragma unroll
    for (int e = 0; e < 8; ++e) { hi[e] = bf_hi(ff[e]); lo[e] = bf_lo(ff[e]); }
}

// ---------------------------------------------------------------------------
// Split-bf16 MFMA NT-GEMM: C[M,1024] = X[M,768] @ Wt[1024,768]^T  (~fp32 acc)
// EPI=0: store transposed bf16 hi/lo:  outT*[b][h][o]  (M == b*64+o)
// EPI=1: store f32 relu(c + bias[h]) * scale[h] row-major [M][1024]
// Block 256 = 4 waves (2x2 of 32x32), K staged 64 at a time in swizzled LDS.
// ---------------------------------------------------------------------------
template<int EPI>
__global__ __launch_bounds__(256)
void gemm_nt_split(const float* __restrict__ X, const float* __restrict__ Wt,
                   const float* __restrict__ bias, const float* __restrict__ scale,
                   float* __restrict__ outF, short* __restrict__ outTh,
                   short* __restrict__ outTl)
{
    __shared__ short Xh[64][64], Xl[64][64], Wh[64][64], Wl[64][64];
    const int r0 = blockIdx.x * 64;
    const int h0 = blockIdx.y * 64;
    const int tid = threadIdx.x;
    const int w = tid >> 6, l = tid & 63;
    const int wm = (w >> 1) * 32, wn = (w & 1) * 32;
    const int g = l >> 4, c16 = l & 15;
    const int srow = tid >> 2, sq = tid & 3;
    const float* xrow = X + (size_t)(r0 + srow) * VD_ + sq * 16;
    const float* wrow = Wt + (size_t)(h0 + srow) * VD_ + sq * 16;

    f32x4 acc[2][2] = {};

    for (int c = 0; c < VD_ / 64; ++c) {
        __syncthreads();
        #pragma unroll
        for (int uu = 0; uu < 2; ++uu) {
            const int us = ((sq * 2 + uu) ^ (srow & 7)) * 8;
            {
                float4 f0 = *(const float4*)(xrow + c * 64 + uu * 8);
                float4 f1 = *(const float4*)(xrow + c * 64 + uu * 8 + 4);
                s16x8 hi, lo; cvt8(f0, f1, hi, lo);
                *(s16x8*)&Xh[srow][us] = hi;
                *(s16x8*)&Xl[srow][us] = lo;
            }
            {
                float4 f0 = *(const float4*)(wrow + c * 64 + uu * 8);
                float4 f1 = *(const float4*)(wrow + c * 64 + uu * 8 + 4);
                s16x8 hi, lo; cvt8(f0, f1, hi, lo);
                *(s16x8*)&Wh[srow][us] = hi;
                *(s16x8*)&Wl[srow][us] = lo;
            }
        }
        __syncthreads();
        #pragma unroll
        for (int s = 0; s < 2; ++s) {
            s16x8 ah[2], al[2], bh[2], bl[2];
            #pragma unroll
            for (int i = 0; i < 2; ++i) {
                const int m = wm + i * 16 + c16;
                const int us = ((s * 4 + g) ^ (m & 7)) * 8;
                ah[i] = *(const s16x8*)&Xh[m][us];
                al[i] = *(const s16x8*)&Xl[m][us];
                const int n = wn + i * 16 + c16;
                const int vs = ((s * 4 + g) ^ (n & 7)) * 8;
                bh[i] = *(const s16x8*)&Wh[n][vs];
                bl[i] = *(const s16x8*)&Wl[n][vs];
            }
            #pragma unroll
            for (int i = 0; i < 2; ++i)
                #pragma unroll
                for (int j = 0; j < 2; ++j) {
                    acc[i][j] = MFMA(ah[i], bh[j], acc[i][j]);
                    acc[i][j] = MFMA(ah[i], bl[j], acc[i][j]);
                    acc[i][j] = MFMA(al[i], bh[j], acc[i][j]);
                }
        }
    }

    #pragma unroll
    for (int i = 0; i < 2; ++i) {
        #pragma unroll
        for (int j = 0; j < 2; ++j) {
            const int h = h0 + wn + j * 16 + c16;
            if (EPI == 0) {
                const int o = wm + i * 16 + g * 4;
                s16x4 hi4, lo4;
                #pragma unroll
                for (int r = 0; r < 4; ++r) {
                    hi4[r] = bf_hi(acc[i][j][r]);
                    lo4[r] = bf_lo(acc[i][j][r]);
                }
                const size_t dst = ((size_t)blockIdx.x * H_ + h) * O_ + o;
                *(s16x4*)&outTh[dst] = hi4;
                *(s16x4*)&outTl[dst] = lo4;
            } else {
                const float bv = bias[h], sv = scale[h];
                #pragma unroll
                for (int r = 0; r < 4; ++r) {
                    const int m = r0 + wm + i * 16 + g * 4 + r;
                    outF[(size_t)m * H_ + h] = fmaxf(acc[i][j][r] + bv, 0.f) * sv;
                }
            }
        }
    }
}

// ---------------------------------------------------------------------------
// Fused: per (b, n-pair) block (64 rows = 2n x 32a).
// v_pre = att1_tile(64x64) @ W[b](64x1024) via split-bf16 MFMA; logits =
// sum_h relu(v_pre+vb)*u; masked softmax; out = att2 @ att1.
// A-frags held in registers; B-frags read from L2 (h-major bf16 hi/lo W).
// ---------------------------------------------------------------------------
__global__ __launch_bounds__(256)
void fused_att2(const float* __restrict__ att1,
                const short* __restrict__ Wth, const short* __restrict__ Wtl,
                const float* __restrict__ ub, const float* __restrict__ vb,
                const int* __restrict__ tags, const int* __restrict__ tptr,
                const float* __restrict__ lbptr, float* __restrict__ out)
{
    __shared__ short Ah[64][64], Al[64][64];
    __shared__ float ao[64][64];
    __shared__ float lgp[4][64];
    __shared__ float sml[64];

    const int blk = blockIdx.x;
    const int b = blk >> 6;
    const int n0 = (blk & 63) * 2;
    const int tid = threadIdx.x;
    const size_t base_row = (size_t)(b * N_ + n0) * A_;   // 64 att1 rows

    {   // stage att1 tile: f32 copy (ao) + swizzled bf16 hi/lo (Ah/Al)
        const int row = tid >> 2, q = tid & 3;
        const float* src = att1 + (base_row + row) * O_ + q * 16;
        #pragma unroll
        for (int uu = 0; uu < 2; ++uu) {
            float4 f0 = *(const float4*)(src + uu * 8);
            float4 f1 = *(const float4*)(src + uu * 8 + 4);
            *(float4*)&ao[row][q * 16 + uu * 8] = f0;
            *(float4*)&ao[row][q * 16 + uu * 8 + 4] = f1;
            const int us = ((q * 2 + uu) ^ (row & 7)) * 8;
            s16x8 hi, lo; cvt8(f0, f1, hi, lo);
            *(s16x8*)&Ah[row][us] = hi;
            *(s16x8*)&Al[row][us] = lo;
        }
    }
    __syncthreads();

    const int w = tid >> 6, l = tid & 63;
    const int g = l >> 4, c16 = l & 15;

    // A fragments, held for the whole h sweep (16 frags = 64 VGPRs)
    s16x8 ahf[4][2], alf[4][2];
    #pragma unroll
    for (int i = 0; i < 4; ++i)
        #pragma unroll
        for (int s = 0; s < 2; ++s) {
            const int m = i * 16 + c16;
            const int us = ((s * 4 + g) ^ (m & 7)) * 8;
            ahf[i][s] = *(const s16x8*)&Ah[m][us];
            alf[i][s] = *(const s16x8*)&Al[m][us];
        }

    const float* u0p = ub + (size_t)(b * N_ + n0) * H_;
    const float* u1p = u0p + H_;

    f32x4 part[4] = {};

    #pragma unroll 2
    for (int nt = 0; nt < 16; ++nt) {
        const int h = w * 256 + nt * 16 + c16;          // this lane's h column
        const short* wph = Wth + ((size_t)(b * H_ + h)) * O_ + g * 8;
        const short* wpl = Wtl + ((size_t)(b * H_ + h)) * O_ + g * 8;
        const s16x8 bh0 = *(const s16x8*)(wph);
        const s16x8 bh1 = *(const s16x8*)(wph + 32);
        const s16x8 bl0 = *(const s16x8*)(wpl);
        const s16x8 bl1 = *(const s16x8*)(wpl + 32);
        const float vbv = vb[h];
        const float uu0 = u0p[h];
        const float uu1 = u1p[h];
        #pragma unroll
        for (int i = 0; i < 4; ++i) {
            f32x4 acc = {};
            acc = MFMA(ahf[i][0], bh0, acc);
            acc = MFMA(alf[i][0], bh0, acc);
            acc = MFMA(ahf[i][0], bl0, acc);
            acc = MFMA(ahf[i][1], bh1, acc);
            acc = MFMA(alf[i][1], bh1, acc);
            acc = MFMA(ahf[i][1], bl1, acc);
            const float uu = (i < 2) ? uu0 : uu1;
            #pragma unroll
            for (int r = 0; r < 4; ++r)
                part[i][r] += fmaxf(acc[r] + vbv, 0.f) * uu;
        }
    }

    // reduce each row's logit over the 16 h-lanes (c16 dimension)
    #pragma unroll
    for (int i = 0; i < 4; ++i)
        #pragma unroll
        for (int r = 0; r < 4; ++r) {
            float v = part[i][r];
            v += __shfl_xor(v, 1, 64);
            v += __shfl_xor(v, 2, 64);
            v += __shfl_xor(v, 4, 64);
            v += __shfl_xor(v, 8, 64);
            if (c16 == 0) lgp[w][i * 16 + g * 4 + r] = v;
        }
    __syncthreads();

    const float tf = (float)(*tptr);
    const float lbv = *lbptr;
    if (tid < 64) {
        const float lsum = lgp[0][tid] + lgp[1][tid] + lgp[2][tid] + lgp[3][tid];
        const float lv = (lsum + lbv) / tf;
        const int tg = tags[base_row + tid];
        sml[tid] = (tg > 0) ? lv : -1e30f;
    }
    __syncthreads();

    if (tid < 128) {
        const int nn = tid >> 6, o = tid & 63;
        const float* lr = &sml[nn * 32];
        float m = -3.0e38f;
        #pragma unroll
        for (int a = 0; a < 32; ++a) m = fmaxf(m, lr[a]);
        float s = 0.f, accum = 0.f;
        #pragma unroll
        for (int a = 0; a < 32; ++a) {
            const float e = __expf(lr[a] - m);
            s += e;
            accum += e * ao[nn * 32 + a][o];
        }
        out[(size_t)(b * N_ + n0 + nn) * O_ + o] = accum / s;
    }
}

extern "C" void kernel_launch(void* const* d_in, const int* in_sizes, int n_in,
                              void* d_out, int out_size, void* d_ws, size_t ws_size,
                              hipStream_t stream)
{
    const float* q    = (const float*)d_in[0];
    const float* att1 = (const float*)d_in[1];
    const float* obj  = (const float*)d_in[2];
    const int*   tags = (const int*)d_in[3];
    const int*   tptr = (const int*)d_in[4];
    const float* vw   = (const float*)d_in[5];
    const float* vb   = (const float*)d_in[6];
    const float* qw   = (const float*)d_in[7];
    const float* qb   = (const float*)d_in[8];
    const float* lw   = (const float*)d_in[9];
    const float* lb   = (const float*)d_in[10];
    float* out = (float*)d_out;

    float* ub  = (float*)d_ws;                               // [2048][1024] f32, 8MB
    short* Wth = (short*)(ub + (size_t)B_ * N_ * H_);        // [16][1024][64] bf16-hi, 2MB
    short* Wtl = Wth + (size_t)B_ * H_ * O_;                 // bf16-lo, 2MB

    // W[b][h][o] (transposed, split bf16) = obj[b,o,:] . vw[h,:]
    gemm_nt_split<0><<<dim3((B_ * O_) / 64, H_ / 64), 256, 0, stream>>>(
        obj, vw, nullptr, nullptr, nullptr, Wth, Wtl);
    // u[b*n][h] = relu(q . qw^T + qb) * lw
    gemm_nt_split<1><<<dim3((B_ * N_) / 64, H_ / 64), 256, 0, stream>>>(
        q, qw, qb, lw, ub, nullptr, nullptr);
    // fused logits -> masked softmax -> att2 @ att1
    fused_att2<<<(B_ * N_) / 2, 256, 0, stream>>>(
        att1, Wth, Wtl, ub, vb, tags, tptr, lb, out);
}